// Round 2
// baseline (204.487 us; speedup 1.0000x reference)
//
#include <hip/hip_runtime.h>

#define NUM_SEG 32
#define MUL 128
#define D 3
#define NUM_PATHS 64
#define ROW (NUM_SEG * MUL * D)   // 12288 floats per batch row

__global__ __launch_bounds__(256) void ftp_kernel(
    const float* __restrict__ x0, const float* __restrict__ x1,
    const float* __restrict__ coeff, const int* __restrict__ idx0,
    const int* __restrict__ idx1, const int* __restrict__ idx2,
    float* __restrict__ out)
{
    const int b   = blockIdx.x;
    const int tid = threadIdx.x;

    // Tiny LDS footprint -> ~7 blocks/CU (VGPR-bound), vs 2 with 48KB staging.
    __shared__ float s_m[NUM_PATHS][D * D];                // m[p][i*3+k]
    __shared__ int   s_seg0[NUM_PATHS];                    // idx0 per path
    __shared__ unsigned char s_plist[NUM_SEG][NUM_PATHS];  // per-segment path lists
    __shared__ int   s_cnt[NUM_SEG];

    if (tid < NUM_SEG) s_cnt[tid] = 0;
    __syncthreads();

    if (tid < NUM_PATHS) {
        const int p  = tid;
        const int i1 = idx1[p];
        s_seg0[p]    = idx0[p];
        const int s2 = idx2[p];
        const int pos = atomicAdd(&s_cnt[s2], 1);
        s_plist[s2][pos] = (unsigned char)p;

        const float* x1row = x1 + (size_t)b * (NUM_SEG * D) + i1 * D;
        const float xj0 = x1row[0], xj1 = x1row[1], xj2 = x1row[2];
        const float* cf = coeff + p * 27;   // coeff[p][i][j][k]
        #pragma unroll
        for (int i = 0; i < D; ++i) {
            #pragma unroll
            for (int k = 0; k < D; ++k) {
                s_m[p][i * 3 + k] = xj0 * cf[i * 9 + 0 + k]
                                  + xj1 * cf[i * 9 + 3 + k]
                                  + xj2 * cf[i * 9 + 6 + k];
            }
        }
    }
    __syncthreads();

    // Thread owns u = tid&127; each wave has uniform s -> uniform control flow.
    const int u  = tid & (MUL - 1);
    const int sg = tid >> 7;               // 0 or 1
    const float* __restrict__ x0row = x0 + (size_t)b * ROW + u * D;
    float* __restrict__ outrow = out + (size_t)b * ROW + u * D;

    for (int s = sg; s < NUM_SEG; s += 2) {
        float acc0 = 0.f, acc1 = 0.f, acc2 = 0.f;
        const int n = s_cnt[s];
        for (int t = 0; t < n; ++t) {
            const int p = s_plist[s][t];
            // Coalesced: wave reads 64 consecutive 12B chunks (768B).
            const float* xs = x0row + s_seg0[p] * (MUL * D);
            const float a0 = xs[0], a1 = xs[1], a2 = xs[2];
            const float* m = s_m[p];       // wave-uniform -> LDS broadcast, free
            acc0 += a0 * m[0] + a1 * m[3] + a2 * m[6];
            acc1 += a0 * m[1] + a1 * m[4] + a2 * m[7];
            acc2 += a0 * m[2] + a1 * m[5] + a2 * m[8];
        }
        // Streaming store: out is write-once, keep it out of x0's L2 window.
        float* o = outrow + s * (MUL * D);
        __builtin_nontemporal_store(acc0, o + 0);
        __builtin_nontemporal_store(acc1, o + 1);
        __builtin_nontemporal_store(acc2, o + 2);
    }
}

extern "C" void kernel_launch(void* const* d_in, const int* in_sizes, int n_in,
                              void* d_out, int out_size, void* d_ws, size_t ws_size,
                              hipStream_t stream) {
    const float* x0    = (const float*)d_in[0];
    const float* x1    = (const float*)d_in[1];
    const float* coeff = (const float*)d_in[2];
    const int*   idx0  = (const int*)d_in[3];
    const int*   idx1  = (const int*)d_in[4];
    const int*   idx2  = (const int*)d_in[5];
    float* out = (float*)d_out;

    const int B = in_sizes[0] / ROW;
    ftp_kernel<<<B, 256, 0, stream>>>(x0, x1, coeff, idx0, idx1, idx2, out);
}